// Round 5
// baseline (118.150 us; speedup 1.0000x reference)
//
#include <hip/hip_runtime.h>

// BinaryTreeRNN, single grid-stride kernel, 2 rows (128 B) per thread per
// iteration, non-temporal streaming loads/stores.
//
// Per row n of x (N x 16, f32):
//   h[l] = leaf_w[l,:] . x[n,:] + leaf_b[l]         (8 leaves)
//   3 tree levels (om3 -> om2 -> om1), each node:
//     s = l + r; out = w*(c0*s + c1*sin s + c2*cos s + c3*l*r) + b,
//     (c0..c3) = softmax(om row). Output h[0] : (N,) f32.
//
// Memory-bound: 256 MB read + 16 MB write -> ~43 us floor @ 6.3 TB/s.
// R4 fix: __builtin_nontemporal_* requires clang vector types, not
// HIP_vector_type structs -> use ext_vector_type(4)/(2) floats.
// Keeps R3 winners: 2048-block grid-stride (fold amortized over 524k
// threads), readfirstlane'd SGPR coefficients, v_sin/v_cos fast trig.

typedef float f32x4 __attribute__((ext_vector_type(4)));
typedef float f32x2 __attribute__((ext_vector_type(2)));

__device__ __forceinline__ float rfl(float v) {
    return __int_as_float(__builtin_amdgcn_readfirstlane(__float_as_int(v)));
}

__device__ __forceinline__ void fast_sincos(float s, float* sn, float* cs) {
#if __has_builtin(__builtin_amdgcn_sinf) && __has_builtin(__builtin_amdgcn_cosf)
    const float INV2PI = 0.15915494309189535f;
    float t = s * INV2PI;
    t = t - floorf(t);               // v_fract: exact mod-1 in revolutions
    *sn = __builtin_amdgcn_sinf(t);  // sin(t * 2pi)
    *cs = __builtin_amdgcn_cosf(t);  // cos(t * 2pi)
#else
    sincosf(s, sn, cs);
#endif
}

__device__ __forceinline__ float node_eval(float l, float r, const float c[5]) {
    float s = l + r;
    float sn, cs;
    fast_sincos(s, &sn, &cs);
    float acc = c[4];
    acc = fmaf(c[3], l * r, acc);
    acc = fmaf(c[2], cs, acc);
    acc = fmaf(c[1], sn, acc);
    acc = fmaf(c[0], s,  acc);
    return acc;
}

__device__ __forceinline__ float row_eval(const f32x4 a[4],
                                          const float* __restrict__ lw,
                                          const float* __restrict__ lb,
                                          const float cf[7][5]) {
    float xv[16] = {a[0].x, a[0].y, a[0].z, a[0].w, a[1].x, a[1].y, a[1].z, a[1].w,
                    a[2].x, a[2].y, a[2].z, a[2].w, a[3].x, a[3].y, a[3].z, a[3].w};
    float h[8];
#pragma unroll
    for (int l = 0; l < 8; ++l) {
        float acc = lb[l];
#pragma unroll
        for (int v = 0; v < 16; ++v) acc = fmaf(lw[l * 16 + v], xv[v], acc);
        h[l] = acc;
    }
    float g4[4];
#pragma unroll
    for (int nd = 0; nd < 4; ++nd) g4[nd] = node_eval(h[2 * nd], h[2 * nd + 1], cf[nd]);
    float g2[2];
    g2[0] = node_eval(g4[0], g4[1], cf[4]);
    g2[1] = node_eval(g4[2], g4[3], cf[5]);
    return node_eval(g2[0], g2[1], cf[6]);
}

__global__ __launch_bounds__(256) void tree_fused(const f32x4* __restrict__ x,
                                                  const float* __restrict__ lw,
                                                  const float* __restrict__ lb,
                                                  const float* __restrict__ w1, const float* __restrict__ b1,
                                                  const float* __restrict__ om1,
                                                  const float* __restrict__ w2, const float* __restrict__ b2,
                                                  const float* __restrict__ om2,
                                                  const float* __restrict__ w3, const float* __restrict__ b3,
                                                  const float* __restrict__ om3,
                                                  f32x2* __restrict__ out2, int nChunks) {
    // One-time coefficient fold (uniform inputs, identical in all lanes),
    // broadcast into SGPRs via readfirstlane.
    float cf[7][5];
#pragma unroll
    for (int nd = 0; nd < 7; ++nd) {
        const float* om;
        float w, b;
        if (nd < 4)      { om = om3 + nd * 4;       w = w3[nd];     b = b3[nd]; }
        else if (nd < 6) { om = om2 + (nd - 4) * 4; w = w2[nd - 4]; b = b2[nd - 4]; }
        else             { om = om1;                w = w1[0];      b = b1[0]; }
        float m  = fmaxf(fmaxf(om[0], om[1]), fmaxf(om[2], om[3]));
        float e0 = __expf(om[0] - m), e1 = __expf(om[1] - m);
        float e2 = __expf(om[2] - m), e3 = __expf(om[3] - m);
        float inv = w / (e0 + e1 + e2 + e3);
        cf[nd][0] = rfl(e0 * inv); cf[nd][1] = rfl(e1 * inv);
        cf[nd][2] = rfl(e2 * inv); cf[nd][3] = rfl(e3 * inv);
        cf[nd][4] = rfl(b);
    }

    int stride = gridDim.x * 256;
    for (int c = blockIdx.x * 256 + threadIdx.x; c < nChunks; c += stride) {
        // 128 B/lane contiguous: 8 back-to-back nt dwordx4 loads (2 rows).
        const f32x4* xp = x + (size_t)c * 8;
        f32x4 a[8];
#pragma unroll
        for (int i = 0; i < 8; ++i) a[i] = __builtin_nontemporal_load(xp + i);

        f32x2 o;
        o.x = row_eval(&a[0], lw, lb, cf);
        o.y = row_eval(&a[4], lw, lb, cf);
        __builtin_nontemporal_store(o, out2 + c);   // coalesced dwordx2
    }
}

extern "C" void kernel_launch(void* const* d_in, const int* in_sizes, int n_in,
                              void* d_out, int out_size, void* d_ws, size_t ws_size,
                              hipStream_t stream) {
    const float* x      = (const float*)d_in[0];
    const float* leaf_w = (const float*)d_in[1];
    const float* leaf_b = (const float*)d_in[2];
    const float* w1     = (const float*)d_in[3];
    const float* b1     = (const float*)d_in[4];
    const float* om1    = (const float*)d_in[5];
    const float* w2     = (const float*)d_in[6];
    const float* b2     = (const float*)d_in[7];
    const float* om2    = (const float*)d_in[8];
    const float* w3     = (const float*)d_in[9];
    const float* b3     = (const float*)d_in[10];
    const float* om3    = (const float*)d_in[11];

    int N = in_sizes[0] / 16;
    int nChunks = N / 2;  // N = 4,000,000 is even; 2 rows per chunk
    f32x2* out2 = (f32x2*)d_out;

    int blocks = 2048;  // 8 blocks/CU, grid-stride
    tree_fused<<<blocks, 256, 0, stream>>>((const f32x4*)x, leaf_w, leaf_b,
                                           w1, b1, om1, w2, b2, om2, w3, b3, om3,
                                           out2, nChunks);
}

// Round 6
// 53.734 us; speedup vs baseline: 2.1988x; 2.1988x over previous
//
#include <hip/hip_runtime.h>

// BinaryTreeRNN, single grid-stride kernel with wave-cooperative coalesced
// staging through LDS.
//
// Per row n of x (N x 16, f32):
//   h[l] = leaf_w[l,:] . x[n,:] + leaf_b[l]         (8 leaves)
//   3 tree levels (om3 -> om2 -> om1), each node:
//     s = l + r; out = w*(c0*s + c1*sin s + c2*cos s + c3*l*r) + b,
//     (c0..c3) = softmax(om row). Output h[0] : (N,) f32.
//
// Memory-bound: 256 MB read + 16 MB write -> ~43 us floor.
// R5 lesson: nt + per-instruction striding = disaster (118 us). Reverted.
// R6 experiment: make every global load instruction fully coalesced
// (lane i reads base + i*16B, 1 KB/instr like memcpy) by staging each
// wave's 64-row tile through LDS. Rows padded to 17 floats (68 B) so the
// per-lane row reads hit banks (17*lane+off)%32 -- bijective, conflict-free.
// Same-wave staging: no __syncthreads, just lgkmcnt(0).
// Keeps R3 winners: 2048-block grid-stride, readfirstlane'd SGPR
// coefficients, v_sin/v_cos fast trig.

typedef float f32x4 __attribute__((ext_vector_type(4)));

__device__ __forceinline__ float rfl(float v) {
    return __int_as_float(__builtin_amdgcn_readfirstlane(__float_as_int(v)));
}

__device__ __forceinline__ void fast_sincos(float s, float* sn, float* cs) {
#if __has_builtin(__builtin_amdgcn_sinf) && __has_builtin(__builtin_amdgcn_cosf)
    const float INV2PI = 0.15915494309189535f;
    float t = s * INV2PI;
    t = t - floorf(t);               // v_fract: exact mod-1 in revolutions
    *sn = __builtin_amdgcn_sinf(t);  // sin(t * 2pi)
    *cs = __builtin_amdgcn_cosf(t);  // cos(t * 2pi)
#else
    sincosf(s, sn, cs);
#endif
}

__device__ __forceinline__ float node_eval(float l, float r, const float c[5]) {
    float s = l + r;
    float sn, cs;
    fast_sincos(s, &sn, &cs);
    float acc = c[4];
    acc = fmaf(c[3], l * r, acc);
    acc = fmaf(c[2], cs, acc);
    acc = fmaf(c[1], sn, acc);
    acc = fmaf(c[0], s,  acc);
    return acc;
}

#define ROW_F 17   // 16 data floats + 1 pad -> conflict-free LDS row reads

__global__ __launch_bounds__(256) void tree_fused(const f32x4* __restrict__ x,
                                                  const float* __restrict__ lw,
                                                  const float* __restrict__ lb,
                                                  const float* __restrict__ w1, const float* __restrict__ b1,
                                                  const float* __restrict__ om1,
                                                  const float* __restrict__ w2, const float* __restrict__ b2,
                                                  const float* __restrict__ om2,
                                                  const float* __restrict__ w3, const float* __restrict__ b3,
                                                  const float* __restrict__ om3,
                                                  float* __restrict__ out, int nTiles) {
    __shared__ float lds[4][64 * ROW_F];
    const int wave = threadIdx.x >> 6;
    const int lane = threadIdx.x & 63;
    float* myLds = lds[wave];

    // One-time coefficient fold (uniform inputs, identical in all lanes),
    // broadcast into SGPRs via readfirstlane.
    float cf[7][5];
#pragma unroll
    for (int nd = 0; nd < 7; ++nd) {
        const float* om;
        float w, b;
        if (nd < 4)      { om = om3 + nd * 4;       w = w3[nd];     b = b3[nd]; }
        else if (nd < 6) { om = om2 + (nd - 4) * 4; w = w2[nd - 4]; b = b2[nd - 4]; }
        else             { om = om1;                w = w1[0];      b = b1[0]; }
        float m  = fmaxf(fmaxf(om[0], om[1]), fmaxf(om[2], om[3]));
        float e0 = __expf(om[0] - m), e1 = __expf(om[1] - m);
        float e2 = __expf(om[2] - m), e3 = __expf(om[3] - m);
        float inv = w / (e0 + e1 + e2 + e3);
        cf[nd][0] = rfl(e0 * inv); cf[nd][1] = rfl(e1 * inv);
        cf[nd][2] = rfl(e2 * inv); cf[nd][3] = rfl(e3 * inv);
        cf[nd][4] = rfl(b);
    }

    const int gwave  = blockIdx.x * 4 + wave;
    const int nWaves = gridDim.x * 4;

    for (int tile = gwave; tile < nTiles; tile += nWaves) {
        // Stage 64 rows (256 float4 = 4 KB) with 4 fully-coalesced loads:
        // instruction i: lane l reads float4 (i*64 + l) -> 1 KB contiguous.
        const f32x4* src = x + (size_t)tile * 256;
#pragma unroll
        for (int i = 0; i < 4; ++i) {
            int j = i * 64 + lane;
            f32x4 v = src[j];
            float* p = myLds + (j >> 2) * ROW_F + (j & 3) * 4;
            p[0] = v.x; p[1] = v.y; p[2] = v.z; p[3] = v.w;
        }
        // Same-wave producer/consumer: DS ops execute in order per wave;
        // drain lgkm and fence the compiler before cross-lane reads.
        asm volatile("s_waitcnt lgkmcnt(0)" ::: "memory");

        float xv[16];
#pragma unroll
        for (int v = 0; v < 16; ++v) xv[v] = myLds[lane * ROW_F + v];

        // 8 leaves; lw/lb uniform -> scalar loads, SGPR-operand FMAs.
        float h[8];
#pragma unroll
        for (int l = 0; l < 8; ++l) {
            float acc = lb[l];
#pragma unroll
            for (int v = 0; v < 16; ++v) acc = fmaf(lw[l * 16 + v], xv[v], acc);
            h[l] = acc;
        }

        float g4[4];
#pragma unroll
        for (int nd = 0; nd < 4; ++nd) g4[nd] = node_eval(h[2 * nd], h[2 * nd + 1], cf[nd]);
        float g2[2];
        g2[0] = node_eval(g4[0], g4[1], cf[4]);
        g2[1] = node_eval(g4[2], g4[3], cf[5]);
        out[tile * 64 + lane] = node_eval(g2[0], g2[1], cf[6]);   // coalesced
    }
}

extern "C" void kernel_launch(void* const* d_in, const int* in_sizes, int n_in,
                              void* d_out, int out_size, void* d_ws, size_t ws_size,
                              hipStream_t stream) {
    const float* x      = (const float*)d_in[0];
    const float* leaf_w = (const float*)d_in[1];
    const float* leaf_b = (const float*)d_in[2];
    const float* w1     = (const float*)d_in[3];
    const float* b1     = (const float*)d_in[4];
    const float* om1    = (const float*)d_in[5];
    const float* w2     = (const float*)d_in[6];
    const float* b2     = (const float*)d_in[7];
    const float* om2    = (const float*)d_in[8];
    const float* w3     = (const float*)d_in[9];
    const float* b3     = (const float*)d_in[10];
    const float* om3    = (const float*)d_in[11];

    int N = in_sizes[0] / 16;
    int nTiles = N / 64;            // N = 4,000,000 = 62500 * 64 exactly
    float* out = (float*)d_out;

    int blocks = 2048;              // 8 blocks/CU, wave-level grid-stride
    tree_fused<<<blocks, 256, 0, stream>>>((const f32x4*)x, leaf_w, leaf_b,
                                           w1, b1, om1, w2, b2, om2, w3, b3, om3,
                                           out, nTiles);
}

// Round 7
// 48.528 us; speedup vs baseline: 2.4347x; 1.1073x over previous
//
#include <hip/hip_runtime.h>

// BinaryTreeRNN, single grid-stride kernel, exact-cover grid.
//
// Per row n of x (N x 16, f32):
//   h[l] = leaf_w[l,:] . x[n,:] + leaf_b[l]         (8 leaves)
//   3 tree levels (om3 -> om2 -> om1), each node:
//     s = l + r; out = w*(c0*s + c1*sin s + c2*cos s + c3*l*r) + b,
//     (c0..c3) = softmax(om row). Output h[0] : (N,) f32.
//
// Memory-bound: 256 MB read + 16 MB write -> ~43 us stream @ 6.3 TB/s.
// Evidence so far: R1(1row/thr, libm trig)=50.7, R3(grid-stride, fast
// trig)=50.9, R6(LDS-staged memcpy-pattern)=53.7, R5(nt+stride)=118.
// => read micro-pattern and compute are off the critical path; residual
// ~7 us is launch/ramp overhead. R7 final levers:
//   - 3125 blocks x 256 thr = 800k threads, exactly 5 rows each
//     (no ragged tail sweep, no bounds check in steady state)
//   - nt store only (write-once stream; loads stay cached/plain)

typedef float f32x4 __attribute__((ext_vector_type(4)));

__device__ __forceinline__ float rfl(float v) {
    return __int_as_float(__builtin_amdgcn_readfirstlane(__float_as_int(v)));
}

__device__ __forceinline__ void fast_sincos(float s, float* sn, float* cs) {
#if __has_builtin(__builtin_amdgcn_sinf) && __has_builtin(__builtin_amdgcn_cosf)
    const float INV2PI = 0.15915494309189535f;
    float t = s * INV2PI;
    t = t - floorf(t);               // v_fract: exact mod-1 in revolutions
    *sn = __builtin_amdgcn_sinf(t);  // sin(t * 2pi)
    *cs = __builtin_amdgcn_cosf(t);  // cos(t * 2pi)
#else
    sincosf(s, sn, cs);
#endif
}

__device__ __forceinline__ float node_eval(float l, float r, const float c[5]) {
    float s = l + r;
    float sn, cs;
    fast_sincos(s, &sn, &cs);
    float acc = c[4];
    acc = fmaf(c[3], l * r, acc);
    acc = fmaf(c[2], cs, acc);
    acc = fmaf(c[1], sn, acc);
    acc = fmaf(c[0], s,  acc);
    return acc;
}

__global__ __launch_bounds__(256) void tree_fused(const f32x4* __restrict__ x,
                                                  const float* __restrict__ lw,
                                                  const float* __restrict__ lb,
                                                  const float* __restrict__ w1, const float* __restrict__ b1,
                                                  const float* __restrict__ om1,
                                                  const float* __restrict__ w2, const float* __restrict__ b2,
                                                  const float* __restrict__ om2,
                                                  const float* __restrict__ w3, const float* __restrict__ b3,
                                                  const float* __restrict__ om3,
                                                  float* __restrict__ out,
                                                  int N, int rowsPerThread) {
    // One-time coefficient fold (uniform inputs, identical in all lanes),
    // broadcast into SGPRs via readfirstlane. Amortized over rowsPerThread.
    float cf[7][5];
#pragma unroll
    for (int nd = 0; nd < 7; ++nd) {
        const float* om;
        float w, b;
        if (nd < 4)      { om = om3 + nd * 4;       w = w3[nd];     b = b3[nd]; }
        else if (nd < 6) { om = om2 + (nd - 4) * 4; w = w2[nd - 4]; b = b2[nd - 4]; }
        else             { om = om1;                w = w1[0];      b = b1[0]; }
        float m  = fmaxf(fmaxf(om[0], om[1]), fmaxf(om[2], om[3]));
        float e0 = __expf(om[0] - m), e1 = __expf(om[1] - m);
        float e2 = __expf(om[2] - m), e3 = __expf(om[3] - m);
        float inv = w / (e0 + e1 + e2 + e3);
        cf[nd][0] = rfl(e0 * inv); cf[nd][1] = rfl(e1 * inv);
        cf[nd][2] = rfl(e2 * inv); cf[nd][3] = rfl(e3 * inv);
        cf[nd][4] = rfl(b);
    }

    const int stride = gridDim.x * 256;
    int n = blockIdx.x * 256 + threadIdx.x;
#pragma unroll 1
    for (int it = 0; it < rowsPerThread; ++it, n += stride) {
        // 64 B/lane contiguous read: 4 x dwordx4, L1 merges across instrs.
        const f32x4* xp = x + (size_t)n * 4;
        f32x4 a0 = xp[0], a1 = xp[1], a2 = xp[2], a3 = xp[3];
        float xv[16] = {a0.x, a0.y, a0.z, a0.w, a1.x, a1.y, a1.z, a1.w,
                        a2.x, a2.y, a2.z, a2.w, a3.x, a3.y, a3.z, a3.w};

        // 8 leaves; lw/lb uniform -> scalar loads, SGPR-operand FMAs.
        float h[8];
#pragma unroll
        for (int l = 0; l < 8; ++l) {
            float acc = lb[l];
#pragma unroll
            for (int v = 0; v < 16; ++v) acc = fmaf(lw[l * 16 + v], xv[v], acc);
            h[l] = acc;
        }

        float g4[4];
#pragma unroll
        for (int nd = 0; nd < 4; ++nd) g4[nd] = node_eval(h[2 * nd], h[2 * nd + 1], cf[nd]);
        float g2[2];
        g2[0] = node_eval(g4[0], g4[1], cf[4]);
        g2[1] = node_eval(g4[2], g4[3], cf[5]);
        float r = node_eval(g2[0], g2[1], cf[6]);
        __builtin_nontemporal_store(r, out + n);   // coalesced, write-once
    }
}

extern "C" void kernel_launch(void* const* d_in, const int* in_sizes, int n_in,
                              void* d_out, int out_size, void* d_ws, size_t ws_size,
                              hipStream_t stream) {
    const float* x      = (const float*)d_in[0];
    const float* leaf_w = (const float*)d_in[1];
    const float* leaf_b = (const float*)d_in[2];
    const float* w1     = (const float*)d_in[3];
    const float* b1     = (const float*)d_in[4];
    const float* om1    = (const float*)d_in[5];
    const float* w2     = (const float*)d_in[6];
    const float* b2     = (const float*)d_in[7];
    const float* om2    = (const float*)d_in[8];
    const float* w3     = (const float*)d_in[9];
    const float* b3     = (const float*)d_in[10];
    const float* om3    = (const float*)d_in[11];

    int N = in_sizes[0] / 16;
    float* out = (float*)d_out;

    // N = 4,000,000 = 3125 blocks * 256 threads * 5 rows exactly.
    int blocks, rowsPerThread;
    if (N % (3125 * 256) == 0) {
        blocks = 3125; rowsPerThread = N / (3125 * 256);
    } else {
        blocks = (N + 255) / 256; rowsPerThread = 1;
    }
    tree_fused<<<blocks, 256, 0, stream>>>((const f32x4*)x, leaf_w, leaf_b,
                                           w1, b1, om1, w2, b2, om2, w3, b3, om3,
                                           out, N, rowsPerThread);
}